// Round 5
// baseline (524.036 us; speedup 1.0000x reference)
//
#include <hip/hip_runtime.h>

#define N_NODES 100000
#define N_EDGES 1600000
#define D 128
#define NBUCK 98          // ceil(N_NODES / 1024), bucket = dst >> 10
#define CAP 20480         // ebuf slab capacity per bucket (raw edges); mean 16384, sigma~127
#define RSTRIDE_U32 800008   // (N_NODES+1) rows * 8 dwords per cg region
#define RSTRIDE_S 1600016    // same in shorts

typedef __attribute__((ext_vector_type(8))) short bf16x8;
typedef __attribute__((ext_vector_type(4))) float f32x4;
typedef unsigned long long u64;

__device__ __forceinline__ float b2f_lo(unsigned int u) {
    return __builtin_bit_cast(float, u << 16);
}
__device__ __forceinline__ float b2f_hi(unsigned int u) {
    return __builtin_bit_cast(float, u & 0xFFFF0000u);
}
__device__ __forceinline__ unsigned short f2b(float f) {
    unsigned int u = __builtin_bit_cast(unsigned int, f);
    u += 0x7FFFu + ((u >> 16) & 1u);
    return (unsigned short)(u >> 16);
}

// ---------------- prep: zero scratch + convert weights + convert x into cg-transposed xbT ----------------
// xbT layout: 8 regions (cg = col/16), region cg holds [node][16 cols] bf16 = 32B/row.
// Per-XCD gather working set becomes 3.2MB (L2-resident) when agg pins cg to XCD.

__global__ __launch_bounds__(256) void prep_kernel(
    const float* __restrict__ x, unsigned int* __restrict__ xbT,
    const float* __restrict__ W0, const float* __restrict__ W1_, const float* __restrict__ W2_,
    const float* __restrict__ W3, const float* __restrict__ W4, const float* __restrict__ W5,
    unsigned short* __restrict__ T0, unsigned short* __restrict__ T1_,
    unsigned short* __restrict__ T2_, unsigned short* __restrict__ T3,
    unsigned short* __restrict__ T4, unsigned short* __restrict__ T5,
    uint4* __restrict__ dob4) {
    int blk = blockIdx.x;
    if (blk < 384) {
        const float* W;
        unsigned short* T;
        switch (blk >> 6) {
            case 0: W = W0; T = T0; break;
            case 1: W = W1_; T = T1_; break;
            case 2: W = W2_; T = T2_; break;
            case 3: W = W3; T = T3; break;
            case 4: W = W4; T = T4; break;
            default: W = W5; T = T5; break;
        }
        int i = (blk & 63) * 256 + threadIdx.x;   // 0..16383
        int k = i >> 7, n = i & 127;
        T[n * 128 + k] = f2b(W[i]);               // [k][n] fp32 -> [n][k] bf16
    } else if (blk < 12884) {
        int i = (blk - 384) * 256 + threadIdx.x;  // float4 chunk id, 3,200,000 total
        if (i < 3200000) {
            float4 v = ((const float4*)x)[i];
            int r = i >> 5;          // node row
            int q = i & 31;          // float4 within row -> bf16 dwords 2q, 2q+1
            int dw = q * 2;          // dword-of-row 0..62
            int cg = dw >> 3;
            int cj = dw & 7;
            uint2 o;
            o.x = (unsigned int)f2b(v.x) | ((unsigned int)f2b(v.y) << 16);
            o.y = (unsigned int)f2b(v.z) | ((unsigned int)f2b(v.w) << 16);
            *(uint2*)(xbT + (size_t)cg * RSTRIDE_U32 + (size_t)r * 8 + cj) = o;
        }
    } else {
        int i = (blk - 12884) * 256 + threadIdx.x;
        uint4 z = {0u, 0u, 0u, 0u};
        if (i < 256) dob4[i] = z;     // zero d_out scratch head [0, 4096) = bcur
        if (i < 64) {                 // zero sentinel row N_NODES in each cg region
            int cg = i >> 3, c = i & 7;
            xbT[(size_t)cg * RSTRIDE_U32 + (size_t)N_NODES * 8 + c] = 0u;
        }
    }
}

// ---------------- CSR build (bucket-local, LDS atomics only, degrees padded to %8) ----------------

// Bin edges into fixed-stride bucket slabs: slab b = ebuf[b*CAP ...].
__global__ __launch_bounds__(256) void bin_kernel(const int* __restrict__ src,
                                                  const int* __restrict__ dst,
                                                  int* __restrict__ bcur,
                                                  u64* __restrict__ ebuf) {
    __shared__ int h[NBUCK];
    __shared__ int base[NBUCK];
    int tid = threadIdx.x;
    if (tid < NBUCK) h[tid] = 0;
    __syncthreads();
    int e0 = blockIdx.x * 2048;
    int myd[8], mys[8];
#pragma unroll
    for (int i = 0; i < 8; i++) {
        int e = e0 + tid + i * 256;
        int dv = (e < N_EDGES) ? dst[e] : -1;
        myd[i] = dv;
        mys[i] = (e < N_EDGES) ? src[e] : 0;
        if (dv >= 0) atomicAdd(&h[dv >> 10], 1);
    }
    __syncthreads();
    if (tid < NBUCK) {
        int c = h[tid];
        base[tid] = (c > 0) ? (tid * CAP + atomicAdd(&bcur[tid], c)) : 0;
        h[tid] = 0;
    }
    __syncthreads();
#pragma unroll
    for (int i = 0; i < 8; i++) {
        int dv = myd[i];
        if (dv >= 0) {
            int b = dv >> 10;
            int p = base[b] + atomicAdd(&h[b], 1);
            if (p < (b + 1) * CAP)
                ebuf[p] = ((u64)(unsigned int)dv << 32) | (unsigned int)mys[i];
        }
    }
}

// Per-bucket: LDS hist of dst -> per-node deg (global) + %8-padded bucket total.
__global__ __launch_bounds__(1024) void bucket_hist_kernel(const u64* __restrict__ ebuf,
                                                           const int* __restrict__ bcur,
                                                           int* __restrict__ deg,
                                                           int* __restrict__ ptot) {
    __shared__ int hist[1024];
    int b = blockIdx.x, tid = threadIdx.x;
    int nE = bcur[b]; if (nE > CAP) nE = CAP;
    const u64* slab = ebuf + (size_t)b * CAP;
    hist[tid] = 0;
    __syncthreads();
    for (int i = tid; i < nE; i += 1024)
        atomicAdd(&hist[(int)(slab[i] >> 32) & 1023], 1);
    __syncthreads();
    int node = b * 1024 + tid;
    int d = hist[tid];
    if (node < N_NODES) deg[node] = d;
    int dp = (node < N_NODES) ? ((d + 7) & ~7) : 0;
    __syncthreads();
    hist[tid] = dp;
    __syncthreads();
#pragma unroll
    for (int s = 512; s > 0; s >>= 1) {
        if (tid < s) hist[tid] += hist[tid + s];
        __syncthreads();
    }
    if (tid == 0) ptot[b] = hist[0];
}

// Exclusive scan of the 98 padded bucket totals; off[N] = padded grand total.
__global__ __launch_bounds__(128) void pscan_kernel(const int* __restrict__ ptot,
                                                    int* __restrict__ bbase,
                                                    int* __restrict__ off) {
    __shared__ int s[128];
    int tid = threadIdx.x;
    int v = (tid < NBUCK) ? ptot[tid] : 0;
    s[tid] = v;
    __syncthreads();
#pragma unroll
    for (int d = 1; d < 128; d <<= 1) {
        int t = (tid >= d) ? s[tid - d] : 0;
        __syncthreads();
        s[tid] += t;
        __syncthreads();
    }
    if (tid < NBUCK) bbase[tid] = s[tid] - v;
    if (tid == 127) off[N_NODES] = s[127];
}

// Per-bucket: padded LDS scan of deg -> off, LDS-atomic scatter into globally
// contiguous padded CSR, pad slots = sentinel N_NODES (zero row in xbT).
// %8 padding lets agg run pure 8-edge rounds, no tail.
__global__ __launch_bounds__(1024) void bucket_csr_kernel(const u64* __restrict__ ebuf,
                                                          const int* __restrict__ bcur,
                                                          const int* __restrict__ deg,
                                                          const int* __restrict__ bbase,
                                                          int* __restrict__ off,
                                                          int* __restrict__ csr) {
    __shared__ int sc[1024];
    __shared__ int cnt[1024];
    int b = blockIdx.x, tid = threadIdx.x;
    int nE = bcur[b]; if (nE > CAP) nE = CAP;
    int base = bbase[b];
    const u64* slab = ebuf + (size_t)b * CAP;
    int node = b * 1024 + tid;
    int d = (node < N_NODES) ? deg[node] : 0;
    int dp = (node < N_NODES) ? ((d + 7) & ~7) : 0;
    sc[tid] = dp;
    cnt[tid] = 0;
    __syncthreads();
#pragma unroll
    for (int s = 1; s < 1024; s <<= 1) {
        int t = (tid >= s) ? sc[tid - s] : 0;
        __syncthreads();
        sc[tid] += t;
        __syncthreads();
    }
    int excl = sc[tid] - dp;
    sc[tid] = excl;
    if (node < N_NODES) off[node] = base + excl;
    __syncthreads();
    for (int i = tid; i < nE; i += 1024) {
        u64 e = slab[i];
        int dd = (int)(e >> 32) & 1023;
        int pos = sc[dd] + atomicAdd(&cnt[dd], 1);
        csr[base + pos] = (int)(e & 0xFFFFFFFFu);
    }
    for (int j = d; j < dp; j++) csr[base + excl + j] = N_NODES;  // <=7 pads/node
}

// ---------------- aggregation over cg-transposed features ----------------
// cg = blockIdx.x & 7: consecutive blocks round-robin across the 8 XCDs, so each
// XCD works one 16-column slice for ALL nodes -> gather working set 3.2MB < 4MB L2.
// Wave = 8 groups of 8 lanes; group owns one node, lane c owns dword c of the 32B
// slice. 8-edge rounds: lane c prefetches csr[k+c], broadcast via width-8 shfl,
// 8 independent 32B-coalesced gathers per round. Stores: 256B contiguous per wave.

__global__ __launch_bounds__(256) void agg_cg(const unsigned int* __restrict__ xbT,
                                              const int* __restrict__ off,
                                              const int* __restrict__ csr,
                                              unsigned int* __restrict__ tT) {
    int cg = blockIdx.x & 7;
    int nb = blockIdx.x >> 3;
    int lane = threadIdx.x & 63;
    int wave = threadIdx.x >> 6;
    int grp = lane >> 3, c = lane & 7;
    const unsigned int* xr = xbT + (size_t)cg * RSTRIDE_U32;
    unsigned int* tr = tT + (size_t)cg * RSTRIDE_U32;
    int node = nb * 32 + wave * 8 + grp;          // grid covers exactly 100000 nodes
    int k = off[node], e = off[node + 1];
    unsigned int me = xr[(size_t)node * 8 + c];
    float alo = b2f_lo(me), ahi = b2f_hi(me);
    for (; k < e; k += 8) {
        int idx = csr[k + c];
#pragma unroll
        for (int i = 0; i < 8; i++) {
            int n = __shfl(idx, i, 8);
            unsigned int v = xr[(size_t)n * 8 + c];
            alo += b2f_lo(v);
            ahi += b2f_hi(v);
        }
    }
    tr[(size_t)node * 8 + c] = (unsigned int)f2b(alo) | ((unsigned int)f2b(ahi) << 16);
}

// ---------------- fused MLP: y = relu(relu(t @ W1 + b1) @ W2 + b2) ----------------
// A is read from the cg-transposed layout; bf16 output is written back to it.
// 2 row-strips (32 rows) per wave. Per-wave LDS 8704 B.

template <bool OUT_F32>
__global__ __launch_bounds__(256) void mlp_mfma(const unsigned short* __restrict__ A,
                                                const unsigned short* __restrict__ W1t,
                                                const float* __restrict__ bias1,
                                                const unsigned short* __restrict__ W2t,
                                                const float* __restrict__ bias2,
                                                void* __restrict__ out) {
    __shared__ char smem[4 * 8704];
    int tid = threadIdx.x;
    int wave = tid >> 6, lane = tid & 63;
    int quad = lane >> 4, mr = lane & 15;
    int m_base = blockIdx.x * 128 + wave * 32;
    int m0 = m_base + mr;       if (m0 >= N_NODES) m0 = N_NODES - 1;
    int m1 = m_base + 16 + mr;  if (m1 >= N_NODES) m1 = N_NODES - 1;

    unsigned short* ust = (unsigned short*)(smem + wave * 8704);  // strip0 @0, strip1 @2176 shorts

    // ---- GEMM1: u = relu(t @ W1 + b1), both strips ----
    // cols [kc*32 + quad*8 .. +7] live in cg = 2*kc + (quad>>1), short offset (quad&1)*8
    bf16x8 a0[4], a1[4];
#pragma unroll
    for (int kc = 0; kc < 4; kc++) {
        size_t rb = (size_t)(2 * kc + (quad >> 1)) * RSTRIDE_S + (size_t)((quad & 1) * 8);
        a0[kc] = *(const bf16x8*)(A + rb + (size_t)m0 * 16);
        a1[kc] = *(const bf16x8*)(A + rb + (size_t)m1 * 16);
    }

    f32x4 acc0[8], acc1[8];
#pragma unroll
    for (int nt = 0; nt < 8; nt++) { acc0[nt] = (f32x4)0.0f; acc1[nt] = (f32x4)0.0f; }
#pragma unroll
    for (int nt = 0; nt < 8; nt++) {
        const unsigned short* wp = W1t + (size_t)(nt * 16 + mr) * D + quad * 8;
#pragma unroll
        for (int kc = 0; kc < 4; kc++) {
            bf16x8 b = *(const bf16x8*)(wp + kc * 32);
            acc0[nt] = __builtin_amdgcn_mfma_f32_16x16x32_bf16(a0[kc], b, acc0[nt], 0, 0, 0);
            acc1[nt] = __builtin_amdgcn_mfma_f32_16x16x32_bf16(a1[kc], b, acc1[nt], 0, 0, 0);
        }
    }
    // C layout: col(n) = mr, row(m in strip) = quad*4 + r
#pragma unroll
    for (int nt = 0; nt < 8; nt++) {
        float bv = bias1[nt * 16 + mr];
#pragma unroll
        for (int r = 0; r < 4; r++) {
            ust[(quad * 4 + r) * 136 + nt * 16 + mr] = f2b(fmaxf(acc0[nt][r] + bv, 0.0f));
            ust[2176 + (quad * 4 + r) * 136 + nt * 16 + mr] = f2b(fmaxf(acc1[nt][r] + bv, 0.0f));
        }
    }

    // ---- GEMM2: y = relu(u @ W2 + b2), both strips ----
#pragma unroll
    for (int kc = 0; kc < 4; kc++) {
        a0[kc] = *(const bf16x8*)&ust[mr * 136 + kc * 32 + quad * 8];
        a1[kc] = *(const bf16x8*)&ust[2176 + mr * 136 + kc * 32 + quad * 8];
    }
#pragma unroll
    for (int nt = 0; nt < 8; nt++) { acc0[nt] = (f32x4)0.0f; acc1[nt] = (f32x4)0.0f; }
#pragma unroll
    for (int nt = 0; nt < 8; nt++) {
        const unsigned short* wp = W2t + (size_t)(nt * 16 + mr) * D + quad * 8;
#pragma unroll
        for (int kc = 0; kc < 4; kc++) {
            bf16x8 b = *(const bf16x8*)(wp + kc * 32);
            acc0[nt] = __builtin_amdgcn_mfma_f32_16x16x32_bf16(a0[kc], b, acc0[nt], 0, 0, 0);
            acc1[nt] = __builtin_amdgcn_mfma_f32_16x16x32_bf16(a1[kc], b, acc1[nt], 0, 0, 0);
        }
    }

    // ---- epilogue: stage each strip in LDS, coalesced store (u-strips dead now) ----
    if (OUT_F32) {
        float* st = (float*)ust;   // 16 x 132 f32 = 8448 B, fits in the 8704 B wave region
        const int S = 132;
        float* op = (float*)out;
#pragma unroll
        for (int s = 0; s < 2; s++) {
#pragma unroll
            for (int nt = 0; nt < 8; nt++) {
                float bv = bias2[nt * 16 + mr];
#pragma unroll
                for (int r = 0; r < 4; r++) {
                    float v = s ? acc1[nt][r] : acc0[nt][r];
                    st[(quad * 4 + r) * S + nt * 16 + mr] = fmaxf(v + bv, 0.0f);
                }
            }
#pragma unroll
            for (int it = 0; it < 8; it++) {
                int linear = lane + it * 64;
                int row = linear >> 5, col = (linear & 31) << 2;
                int gm = m_base + s * 16 + row;
                if (gm < N_NODES) {
                    float4 val = *(float4*)&st[row * S + col];
                    *(float4*)(op + (size_t)gm * D + col) = val;
                }
            }
        }
    } else {
        const int S = 136;
        unsigned short* op = (unsigned short*)out;   // xbT base
#pragma unroll
        for (int s = 0; s < 2; s++) {
            unsigned short* st = ust + s * 2176;
#pragma unroll
            for (int nt = 0; nt < 8; nt++) {
                float bv = bias2[nt * 16 + mr];
#pragma unroll
                for (int r = 0; r < 4; r++) {
                    float v = s ? acc1[nt][r] : acc0[nt][r];
                    st[(quad * 4 + r) * S + nt * 16 + mr] = f2b(fmaxf(v + bv, 0.0f));
                }
            }
#pragma unroll
            for (int it = 0; it < 4; it++) {
                int linear = lane + it * 64;
                int row = linear >> 4, colst = (linear & 15) << 3;  // colst in {0,8,...,120}
                int gm = m_base + s * 16 + row;
                if (gm < N_NODES) {
                    uint4 val = *(uint4*)&st[row * S + colst];
                    unsigned short* dp = op + (size_t)(colst >> 4) * RSTRIDE_S
                                       + (size_t)gm * 16 + (colst & 15);
                    *(uint4*)dp = val;
                }
            }
        }
    }
}

// ---------------- launch ----------------

extern "C" void kernel_launch(void* const* d_in, const int* in_sizes, int n_in,
                              void* d_out, int out_size, void* d_ws, size_t ws_size,
                              hipStream_t stream) {
    const float* x = (const float*)d_in[0];
    const int* ei = (const int*)d_in[1];
    const int* srcv = ei;
    const int* dstv = ei + N_EDGES;
    const float* W1[3] = {(const float*)d_in[2], (const float*)d_in[6], (const float*)d_in[10]};
    const float* b1[3] = {(const float*)d_in[3], (const float*)d_in[7], (const float*)d_in[11]};
    const float* W2[3] = {(const float*)d_in[4], (const float*)d_in[8], (const float*)d_in[12]};
    const float* b2[3] = {(const float*)d_in[5], (const float*)d_in[9], (const float*)d_in[13]};

    // ws layout (high-water 51,798,528):
    char* ws = (char*)d_ws;
    int* off = (int*)ws;                                     // (N+1) ints @ 0
    unsigned short* Wt[6];                                   // 6 x 32KB @ 401,408
    for (int i = 0; i < 6; i++) Wt[i] = (unsigned short*)(ws + 401408 + i * 32768);
    unsigned short* xbT = (unsigned short*)(ws + 598016);    // 8 cg regions, 25,600,256 B
    unsigned short* PT  = (unsigned short*)(ws + 26198272);  // same, ends 51,798,528

    // d_out scratch (dead before the final MLP overwrites all of d_out; 51.2MB total):
    char* dob = (char*)d_out;
    int* bcur  = (int*)(dob);               // NBUCK ints (zeroed by prep)
    int* deg   = (int*)(dob + 4096);        // N ints
    int* ptot  = (int*)(dob + 450560);      // NBUCK ints
    int* bbase = (int*)(dob + 454656);      // NBUCK ints
    u64* ebuf  = (u64*)(dob + 1048576);     // NBUCK*CAP u64 = 16.06MB, ends 17,104,896
    int* csr   = (int*)(dob + 17104896);    // padded CSR <= E+7N ints = 9.2MB, ends ~26.3MB

    // --- prep: zero bcur + sentinel rows + convert weights + convert x -> xbT ---
    prep_kernel<<<12885, 256, 0, stream>>>(
        x, (unsigned int*)xbT,
        W1[0], W2[0], W1[1], W2[1], W1[2], W2[2],
        Wt[0], Wt[1], Wt[2], Wt[3], Wt[4], Wt[5],
        (uint4*)dob);

    // --- CSR build (bucket-local, padded to %8 per node) ---
    bin_kernel<<<782, 256, 0, stream>>>(srcv, dstv, bcur, ebuf);
    bucket_hist_kernel<<<NBUCK, 1024, 0, stream>>>(ebuf, bcur, deg, ptot);
    pscan_kernel<<<1, 128, 0, stream>>>(ptot, bbase, off);
    bucket_csr_kernel<<<NBUCK, 1024, 0, stream>>>(ebuf, bcur, deg, bbase, off, csr);

    const int agg_grid = 25000;                        // 8 cg x 3125 node-blocks (32 nodes each)
    const int mlp_grid = (N_NODES + 127) / 128;        // 782 (2 strips/wave)

    // layer 0: agg xbT->PT, mlp PT->xbT
    agg_cg<<<agg_grid, 256, 0, stream>>>((const unsigned int*)xbT, off, csr, (unsigned int*)PT);
    mlp_mfma<false><<<mlp_grid, 256, 0, stream>>>(PT, Wt[0], b1[0], Wt[1], b2[0], xbT);
    // layer 1
    agg_cg<<<agg_grid, 256, 0, stream>>>((const unsigned int*)xbT, off, csr, (unsigned int*)PT);
    mlp_mfma<false><<<mlp_grid, 256, 0, stream>>>(PT, Wt[2], b1[1], Wt[3], b2[1], xbT);
    // layer 2
    agg_cg<<<agg_grid, 256, 0, stream>>>((const unsigned int*)xbT, off, csr, (unsigned int*)PT);
    mlp_mfma<true><<<mlp_grid, 256, 0, stream>>>(PT, Wt[4], b1[2], Wt[5], b2[2], d_out);
}